// Round 8
// baseline (1874.662 us; speedup 1.0000x reference)
//
#include <hip/hip_runtime.h>

// RNNDoubleStacked: P=4096 particles, F=128 max features (ragged), H=128 hidden.
// R7 post-mortem: step cost = latency chain + LDS-UNIT SERIALIZATION (~12 cyc
// per wave-instr through the one per-CU LDS pipe). net1 (380 us) is fully
// LDS-pipe-bound: 64 broadcast b128/block-step. Fix both kernels by tiling to
// minimize LDS instructions:
//   lane = (og16, jg): og16 = 16 output groups x 8 outputs; jg = 16-way inner
//   split, 8-float slice -> 2 rotated ds_read_b128 per lane, 64 FMA,
//   4-stage DPP reduce-scatter (xor8/xor4/xor2/xor1 - all VALU), 1 tanh/lane,
//   conflict-free b32 writes. net2 keeps chunked LDS U staging (R6/R7).

constexpr int PN = 4096;
constexpr int FN = 128;
constexpr int HN = 128;
constexpr int CH  = 64;            // steps per staged U chunk (net2)
constexpr int NCH = PN / CH;       // 64 chunks

__device__ __forceinline__ float fast_tanh(float x) {
    // tanh(x) = 1 - 2/(exp(2x)+1); correct +-1 limits via __expf saturation.
    float e = __expf(2.0f * x);
    return 1.0f - 2.0f / (e + 1.0f);
}

// Raw workgroup barrier WITHOUT a vmcnt(0) drain: lgkmcnt(0) publishes this
// wave's ds_write before it signals arrival; "memory" clobber pins LDS ops.
__device__ __forceinline__ void lds_barrier() {
    asm volatile("s_waitcnt lgkmcnt(0)\n\ts_barrier" ::: "memory");
}

// --- DPP cross-lane ops (VALU latency; partners all within the 16-lane row) ---
__device__ __forceinline__ float dpp_xor1(float x) {      // lane^1
    return __int_as_float(__builtin_amdgcn_update_dpp(
        0, __float_as_int(x), 0xB1 /*quad_perm 1,0,3,2*/, 0xF, 0xF, true));
}
__device__ __forceinline__ float dpp_xor2(float x) {      // lane^2
    return __int_as_float(__builtin_amdgcn_update_dpp(
        0, __float_as_int(x), 0x4E /*quad_perm 2,3,0,1*/, 0xF, 0xF, true));
}
__device__ __forceinline__ float dpp_xor4(float x, bool hi) { // lane^4
    int a = __builtin_amdgcn_update_dpp(0, __float_as_int(x), 0x104, 0xF, 0xF, true); // row_shl:4
    int b = __builtin_amdgcn_update_dpp(0, __float_as_int(x), 0x114, 0xF, 0xF, true); // row_shr:4
    return __int_as_float(hi ? b : a);
}
__device__ __forceinline__ float dpp_xor8(float x, bool hi) { // lane^8
    int a = __builtin_amdgcn_update_dpp(0, __float_as_int(x), 0x108, 0xF, 0xF, true); // row_shl:8
    int b = __builtin_amdgcn_update_dpp(0, __float_as_int(x), 0x118, 0xF, 0xF, true); // row_shr:8
    return __int_as_float(hi ? b : a);
}

// Full 16-lane reduce-scatter over 8 accumulators. On return every lane holds
// the complete sum for output-column cidx = hi8*4 + hi4*2 + hi2 (jg-pairs dup).
__device__ __forceinline__ float reduce16(const float s[8], int jg) {
    const bool hi8 = (jg & 8) != 0;
    float m0 = hi8 ? s[0] : s[4], k0 = hi8 ? s[4] : s[0];
    float m1 = hi8 ? s[1] : s[5], k1 = hi8 ? s[5] : s[1];
    float m2 = hi8 ? s[2] : s[6], k2 = hi8 ? s[6] : s[2];
    float m3 = hi8 ? s[3] : s[7], k3 = hi8 ? s[7] : s[3];
    float x0 = k0 + dpp_xor8(m0, hi8);
    float x1 = k1 + dpp_xor8(m1, hi8);
    float x2 = k2 + dpp_xor8(m2, hi8);
    float x3 = k3 + dpp_xor8(m3, hi8);
    const bool hi4 = (jg & 4) != 0;
    float y0 = (hi4 ? x2 : x0) + dpp_xor4(hi4 ? x0 : x2, hi4);
    float y1 = (hi4 ? x3 : x1) + dpp_xor4(hi4 ? x1 : x3, hi4);
    const bool hi2 = (jg & 2) != 0;
    float z  = (hi2 ? y1 : y0) + dpp_xor2(hi2 ? y0 : y1);
    z += dpp_xor1(z);
    return z;
}
__device__ __forceinline__ int reduce16_cidx(int jg) {
    return ((jg >> 3) & 1) * 4 + ((jg >> 2) & 1) * 2 + ((jg >> 1) & 1);
}

__global__ __launch_bounds__(256) void net1_kernel(
    const float* __restrict__ event,
    const int*   __restrict__ lengths,
    const float* __restrict__ W_ih1,
    const float* __restrict__ W_hh1,
    const float* __restrict__ b_ih1,
    const float* __restrict__ b_hh1,
    const float* __restrict__ W_ih2,
    const float* __restrict__ b_ih2,
    const float* __restrict__ b_hh2,
    float* __restrict__ U)
{
    const int p    = blockIdx.x;
    const int tid  = threadIdx.x;
    const int wv   = tid >> 6;                 // wave 0..3
    const int lane = tid & 63;
    const int jg   = lane & 15;                // inner group: slice [jg*8, jg*8+8)
    const int og16 = (wv << 2) + (lane >> 4);  // output group 0..15 (8 outputs)
    const int rot  = (jg >> 2) & 1;            // bank decorrelation (<=2-way: free)
    const int oi_w = og16 * 8 + reduce16_cidx(jg); // this lane's final output

    __shared__ float h[2][HN];                 // double-buffered hidden state
    __shared__ float ev[FN];                   // this particle's input sequence

    if (tid < FN) ev[tid]   = event[p * FN + tid];   // coalesced ([P,F,1])
    if (tid < HN) h[0][tid] = 0.0f;

    // w[c][4t+e] = W_hh1[og16*8+c][jg*8 + 4*((t+rot)&1) + e] — rotation baked
    // into LOAD order so FMA register indices stay compile-time.
    float w[8][8];
    #pragma unroll
    for (int c = 0; c < 8; ++c) {
        const float* row = W_hh1 + (og16 * 8 + c) * HN + jg * 8;
        #pragma unroll
        for (int t = 0; t < 2; ++t) {
            const int krot = (t + rot) & 1;
            float4 v = *reinterpret_cast<const float4*>(row + 4 * krot);
            w[c][4*t+0] = v.x; w[c][4*t+1] = v.y;
            w[c][4*t+2] = v.z; w[c][4*t+3] = v.w;
        }
    }
    const float wx_own   = W_ih1[oi_w];        // x-term joins at the reduce lane
    const float bias_own = b_ih1[oi_w] + b_hh1[oi_w];
    const int   len      = lengths[p];         // uniform across block, in [1,127)

    __syncthreads();

    // Reference freezes h past len -> stop at len.
    for (int t = 0; t < len; ++t) {
        const int cur = t & 1;
        const float x = ev[t];                 // 1 b32 broadcast

        // 2 rotated b128 reads of the 8-float slice; each feeds 8 outputs.
        const float* base = &h[cur][jg * 8];
        float s[8] = {0,0,0,0,0,0,0,0};
        #pragma unroll
        for (int tt = 0; tt < 2; ++tt) {
            const int krot = (tt + rot) & 1;   // runtime only in the ADDRESS
            float4 hv = *reinterpret_cast<const float4*>(base + 4 * krot);
            #pragma unroll
            for (int c = 0; c < 8; ++c) {
                s[c] = fmaf(w[c][4*tt+0], hv.x, s[c]);
                s[c] = fmaf(w[c][4*tt+1], hv.y, s[c]);
                s[c] = fmaf(w[c][4*tt+2], hv.z, s[c]);
                s[c] = fmaf(w[c][4*tt+3], hv.w, s[c]);
            }
        }
        const float z  = reduce16(s, jg);
        const float hn = fast_tanh(z + fmaf(wx_own, x, bias_own));
        if ((jg & 1) == 0) h[cur ^ 1][oi_w] = hn;   // 32 lanes/wave, distinct banks
        lds_barrier();
    }

    // Tail (once per block): U[p][i] = h1 . W_ih2_row_i + b_ih2[i] + b_hh2[i].
    if (tid < HN) {
        const float4* h4 = reinterpret_cast<const float4*>(h[len & 1]);
        const float4* w2 = reinterpret_cast<const float4*>(W_ih2 + tid * HN);
        float a0 = b_ih2[tid] + b_hh2[tid], a1 = 0.f, a2 = 0.f, a3 = 0.f;
        #pragma unroll
        for (int k = 0; k < HN / 4; ++k) {
            float4 hv = h4[k];
            float4 wv = w2[k];
            a0 = fmaf(wv.x, hv.x, a0);
            a1 = fmaf(wv.y, hv.y, a1);
            a2 = fmaf(wv.z, hv.z, a2);
            a3 = fmaf(wv.w, hv.w, a3);
        }
        U[p * HN + tid] = (a0 + a1) + (a2 + a3);    // coalesced
    }
}

__global__ __launch_bounds__(256) void net2_kernel(
    const float* __restrict__ U,
    const float* __restrict__ W_hh2,
    float* __restrict__ out)
{
    const int tid  = threadIdx.x;
    const int wv   = tid >> 6;                 // wave 0..3
    const int lane = tid & 63;
    const int jg   = lane & 15;                // inner group: slice [jg*8, jg*8+8)
    const int og16 = (wv << 2) + (lane >> 4);  // output group 0..15 (8 outputs)
    const int rot  = (jg >> 2) & 1;
    const int oi_w = og16 * 8 + reduce16_cidx(jg);

    __shared__ float h[2][HN];                 // double-buffered hidden state
    __shared__ float Ulds[2][CH * HN];         // double-buffered U panel (2 x 32 KB)

    float w[8][8];
    #pragma unroll
    for (int c = 0; c < 8; ++c) {
        const float* row = W_hh2 + (og16 * 8 + c) * HN + jg * 8;
        #pragma unroll
        for (int t = 0; t < 2; ++t) {
            const int krot = (t + rot) & 1;
            float4 v = *reinterpret_cast<const float4*>(row + 4 * krot);
            w[c][4*t+0] = v.x; w[c][4*t+1] = v.y;
            w[c][4*t+2] = v.z; w[c][4*t+3] = v.w;
        }
    }

    // Stage chunk 0 synchronously (8 coalesced float4 per thread).
    {
        const float4* g = reinterpret_cast<const float4*>(U);
        float4*       l = reinterpret_cast<float4*>(&Ulds[0][0]);
        #pragma unroll
        for (int r = 0; r < 8; ++r) l[r * 256 + tid] = g[r * 256 + tid];
    }
    if (tid < HN) h[0][tid] = 0.0f;
    __syncthreads();

    int buf = 0;
    for (int c = 0; c < NCH; ++c) {
        const int nb = buf ^ 1;

        // Issue-early: chunk c+1 global loads into registers; in flight across
        // the whole chunk (~30K cyc of slack >> HBM latency).
        float4 st[8];
        const int cg = (c + 1 < NCH) ? (c + 1) : c;
        {
            const float4* gsrc = reinterpret_cast<const float4*>(U + cg * CH * HN);
            #pragma unroll
            for (int r = 0; r < 8; ++r) st[r] = gsrc[r * 256 + tid];
        }

        for (int s2 = 0; s2 < CH; ++s2) {
            const int hc = s2 & 1;             // CH even -> parity restarts at 0
            const float u_cur = Ulds[buf][s2 * HN + oi_w];  // b32, banks spread

            const float* base = &h[hc][jg * 8];
            float s[8] = {0,0,0,0,0,0,0,0};
            #pragma unroll
            for (int tt = 0; tt < 2; ++tt) {
                const int krot = (tt + rot) & 1;
                float4 hv = *reinterpret_cast<const float4*>(base + 4 * krot);
                #pragma unroll
                for (int cc = 0; cc < 8; ++cc) {
                    s[cc] = fmaf(w[cc][4*tt+0], hv.x, s[cc]);
                    s[cc] = fmaf(w[cc][4*tt+1], hv.y, s[cc]);
                    s[cc] = fmaf(w[cc][4*tt+2], hv.z, s[cc]);
                    s[cc] = fmaf(w[cc][4*tt+3], hv.w, s[cc]);
                }
            }
            const float z  = reduce16(s, jg);
            const float hn = fast_tanh(z + u_cur);
            if ((jg & 1) == 0) h[hc ^ 1][oi_w] = hn;   // 32 lanes/wave, distinct banks
            lds_barrier();                     // lgkm-only: prefetch stays in flight
        }

        // Write-late: publish staged chunk; the vmcnt wait here is ~free
        // (loads issued 64 steps ago). One full barrier per 64 steps.
        {
            float4* ldst = reinterpret_cast<float4*>(&Ulds[nb][0]);
            #pragma unroll
            for (int r = 0; r < 8; ++r) ldst[r * 256 + tid] = st[r];
        }
        __syncthreads();
        buf = nb;
    }

    if (tid < HN) out[tid] = h[0][tid];        // each chunk ends at parity 0
}

extern "C" void kernel_launch(void* const* d_in, const int* in_sizes, int n_in,
                              void* d_out, int out_size, void* d_ws, size_t ws_size,
                              hipStream_t stream)
{
    const float* event   = (const float*)d_in[0];
    const int*   lengths = (const int*)  d_in[1];
    const float* W_ih1   = (const float*)d_in[2];
    const float* W_hh1   = (const float*)d_in[3];
    const float* b_ih1   = (const float*)d_in[4];
    const float* b_hh1   = (const float*)d_in[5];
    const float* W_ih2   = (const float*)d_in[6];
    const float* W_hh2   = (const float*)d_in[7];
    const float* b_ih2   = (const float*)d_in[8];
    const float* b_hh2   = (const float*)d_in[9];
    float* out = (float*)d_out;                // 128 floats
    float* U   = (float*)d_ws;                 // PN*HN floats = 2 MB scratch

    hipLaunchKernelGGL(net1_kernel, dim3(PN), dim3(256), 0, stream,
                       event, lengths, W_ih1, W_hh1, b_ih1, b_hh1,
                       W_ih2, b_ih2, b_hh2, U);
    hipLaunchKernelGGL(net2_kernel, dim3(1), dim3(256), 0, stream,
                       U, W_hh2, out);
}

// Round 9
// 1763.336 us; speedup vs baseline: 1.0631x; 1.0631x over previous
//
#include <hip/hip_runtime.h>

// RNNDoubleStacked: P=4096 particles, F=128 max features (ragged), H=128 hidden.
// R8 post-mortem: jg16 hurt net2 (deeper reduce + conflicts); jg8 (R7) is the
// step-structure optimum at ~835 cyc/step. Best pieces: net1-R8 (320us) +
// net2-R7 (1424us). This round overlaps them: net2's chunk c only needs
// particles [64c,64c+64), so net2 spin-waits per chunk on device-scope
// ready-counters that net1 blocks bump after storing their U row.
//   producer: U stores -> __syncthreads (vmcnt drain) -> one
//             fetch_add(cnt[p>>6], RELEASE, AGENT) per block.
//   consumer: spin load(cnt[c], ACQUIRE, AGENT) < 64 with s_sleep backoff,
//             then stage the chunk. Only chunk 0 ever stalls (~10us).
// Inner loops byte-identical to proven R7-net2 / R8-net1 (absmax 0, 0 confl).

constexpr int PN = 4096;
constexpr int FN = 128;
constexpr int HN = 128;
constexpr int CH  = 64;            // steps per staged U chunk (net2) = particles/chunk
constexpr int NCH = PN / CH;       // 64 chunks

__device__ __forceinline__ float fast_tanh(float x) {
    float e = __expf(2.0f * x);
    return 1.0f - 2.0f / (e + 1.0f);
}

// Raw workgroup barrier WITHOUT a vmcnt(0) drain: lgkmcnt(0) publishes this
// wave's ds_write before it signals arrival; "memory" clobber pins LDS ops.
__device__ __forceinline__ void lds_barrier() {
    asm volatile("s_waitcnt lgkmcnt(0)\n\ts_barrier" ::: "memory");
}

// --- DPP cross-lane ops (VALU; partners within the 16-lane DPP row) ---
__device__ __forceinline__ float dpp_xor1(float x) {
    return __int_as_float(__builtin_amdgcn_update_dpp(
        0, __float_as_int(x), 0xB1, 0xF, 0xF, true));
}
__device__ __forceinline__ float dpp_xor2(float x) {
    return __int_as_float(__builtin_amdgcn_update_dpp(
        0, __float_as_int(x), 0x4E, 0xF, 0xF, true));
}
__device__ __forceinline__ float dpp_xor4(float x, bool hi) {
    int a = __builtin_amdgcn_update_dpp(0, __float_as_int(x), 0x104, 0xF, 0xF, true);
    int b = __builtin_amdgcn_update_dpp(0, __float_as_int(x), 0x114, 0xF, 0xF, true);
    return __int_as_float(hi ? b : a);
}
__device__ __forceinline__ float dpp_xor8(float x, bool hi) {
    int a = __builtin_amdgcn_update_dpp(0, __float_as_int(x), 0x108, 0xF, 0xF, true);
    int b = __builtin_amdgcn_update_dpp(0, __float_as_int(x), 0x118, 0xF, 0xF, true);
    return __int_as_float(hi ? b : a);
}

// 16-lane reduce-scatter over 8 accumulators (net1, jg16 tiling).
__device__ __forceinline__ float reduce16(const float s[8], int jg) {
    const bool hi8 = (jg & 8) != 0;
    float m0 = hi8 ? s[0] : s[4], k0 = hi8 ? s[4] : s[0];
    float m1 = hi8 ? s[1] : s[5], k1 = hi8 ? s[5] : s[1];
    float m2 = hi8 ? s[2] : s[6], k2 = hi8 ? s[6] : s[2];
    float m3 = hi8 ? s[3] : s[7], k3 = hi8 ? s[7] : s[3];
    float x0 = k0 + dpp_xor8(m0, hi8);
    float x1 = k1 + dpp_xor8(m1, hi8);
    float x2 = k2 + dpp_xor8(m2, hi8);
    float x3 = k3 + dpp_xor8(m3, hi8);
    const bool hi4 = (jg & 4) != 0;
    float y0 = (hi4 ? x2 : x0) + dpp_xor4(hi4 ? x0 : x2, hi4);
    float y1 = (hi4 ? x3 : x1) + dpp_xor4(hi4 ? x1 : x3, hi4);
    const bool hi2 = (jg & 2) != 0;
    float z  = (hi2 ? y1 : y0) + dpp_xor2(hi2 ? y0 : y1);
    z += dpp_xor1(z);
    return z;
}
__device__ __forceinline__ int reduce16_cidx(int jg) {
    return ((jg >> 3) & 1) * 4 + ((jg >> 2) & 1) * 2 + ((jg >> 1) & 1);
}

// ---------------- net1: per-particle RNN (R8 structure) ----------------
template <bool SYNC>
__global__ __launch_bounds__(256) void net1_kernel(
    const float* __restrict__ event,
    const int*   __restrict__ lengths,
    const float* __restrict__ W_ih1,
    const float* __restrict__ W_hh1,
    const float* __restrict__ b_ih1,
    const float* __restrict__ b_hh1,
    const float* __restrict__ W_ih2,
    const float* __restrict__ b_ih2,
    const float* __restrict__ b_hh2,
    float* __restrict__ U,
    unsigned*   cnt)
{
    const int p    = blockIdx.x;
    const int tid  = threadIdx.x;
    const int wv   = tid >> 6;
    const int lane = tid & 63;
    const int jg   = lane & 15;                // 8-float inner slice
    const int og16 = (wv << 2) + (lane >> 4);  // 16 groups x 8 outputs
    const int rot  = (jg >> 2) & 1;
    const int oi_w = og16 * 8 + reduce16_cidx(jg);

    __shared__ float h[2][HN];
    __shared__ float ev[FN];

    if (tid < FN) ev[tid]   = event[p * FN + tid];
    if (tid < HN) h[0][tid] = 0.0f;

    float w[8][8];
    #pragma unroll
    for (int c = 0; c < 8; ++c) {
        const float* row = W_hh1 + (og16 * 8 + c) * HN + jg * 8;
        #pragma unroll
        for (int t = 0; t < 2; ++t) {
            const int krot = (t + rot) & 1;
            float4 v = *reinterpret_cast<const float4*>(row + 4 * krot);
            w[c][4*t+0] = v.x; w[c][4*t+1] = v.y;
            w[c][4*t+2] = v.z; w[c][4*t+3] = v.w;
        }
    }
    const float wx_own   = W_ih1[oi_w];
    const float bias_own = b_ih1[oi_w] + b_hh1[oi_w];
    const int   len      = lengths[p];

    __syncthreads();

    for (int t = 0; t < len; ++t) {
        const int cur = t & 1;
        const float x = ev[t];
        const float* base = &h[cur][jg * 8];
        float s[8] = {0,0,0,0,0,0,0,0};
        #pragma unroll
        for (int tt = 0; tt < 2; ++tt) {
            const int krot = (tt + rot) & 1;
            float4 hv = *reinterpret_cast<const float4*>(base + 4 * krot);
            #pragma unroll
            for (int c = 0; c < 8; ++c) {
                s[c] = fmaf(w[c][4*tt+0], hv.x, s[c]);
                s[c] = fmaf(w[c][4*tt+1], hv.y, s[c]);
                s[c] = fmaf(w[c][4*tt+2], hv.z, s[c]);
                s[c] = fmaf(w[c][4*tt+3], hv.w, s[c]);
            }
        }
        const float z  = reduce16(s, jg);
        const float hn = fast_tanh(z + fmaf(wx_own, x, bias_own));
        if ((jg & 1) == 0) h[cur ^ 1][oi_w] = hn;
        lds_barrier();
    }

    // Tail: U[p][i] = h1 . W_ih2_row_i + b_ih2[i] + b_hh2[i]
    if (tid < HN) {
        const float4* h4 = reinterpret_cast<const float4*>(h[len & 1]);
        const float4* w2 = reinterpret_cast<const float4*>(W_ih2 + tid * HN);
        float a0 = b_ih2[tid] + b_hh2[tid], a1 = 0.f, a2 = 0.f, a3 = 0.f;
        #pragma unroll
        for (int k = 0; k < HN / 4; ++k) {
            float4 hv = h4[k];
            float4 wv = w2[k];
            a0 = fmaf(wv.x, hv.x, a0);
            a1 = fmaf(wv.y, hv.y, a1);
            a2 = fmaf(wv.z, hv.z, a2);
            a3 = fmaf(wv.w, hv.w, a3);
        }
        U[p * HN + tid] = (a0 + a1) + (a2 + a3);
    }

    if (SYNC) {
        __syncthreads();   // each wave drains its U stores (vmcnt 0) before arrival
        if (tid == 0) {
            // release+agent: L2 writeback so net2's XCD sees U before the count
            __hip_atomic_fetch_add(&cnt[p >> 6], 1u,
                                   __ATOMIC_RELEASE, __HIP_MEMORY_SCOPE_AGENT);
        }
    }
}

// ---------------- net2: sequential RNN over particles (R7 structure) ----------------
__device__ __forceinline__ void wait_chunk(const unsigned* cnt, int c) {
    while (__hip_atomic_load(&cnt[c], __ATOMIC_ACQUIRE,
                             __HIP_MEMORY_SCOPE_AGENT) < (unsigned)CH) {
        __builtin_amdgcn_s_sleep(8);           // ~512 cyc backoff per poll
    }
}

template <bool SYNC>
__global__ __launch_bounds__(256) void net2_kernel(
    const float* __restrict__ U,
    const float* __restrict__ W_hh2,
    float* __restrict__ out,
    const unsigned* cnt)
{
    const int tid  = threadIdx.x;
    const int wv   = tid >> 6;                 // wave 0..3
    const int lane = tid & 63;
    const int jg   = lane & 7;                 // 16-float inner slice
    const int ogl  = lane >> 3;
    const int og   = (wv << 3) + ogl;          // 32 groups x 4 outputs
    const int rot  = jg >> 1;
    const bool hi4 = (jg & 4) != 0;
    const int cidx = ((jg >> 2) & 1) * 2 + ((jg >> 1) & 1);
    const int oi_w = og * 4 + cidx;

    __shared__ float h[2][HN];
    __shared__ float Ulds[2][CH * HN];         // 2 x 32 KB U panels

    float w[4][16];
    #pragma unroll
    for (int c = 0; c < 4; ++c) {
        const float* row = W_hh2 + (og * 4 + c) * HN + jg * 16;
        #pragma unroll
        for (int t = 0; t < 4; ++t) {
            const int krot = (t + rot) & 3;
            float4 v = *reinterpret_cast<const float4*>(row + 4 * krot);
            w[c][4*t+0] = v.x; w[c][4*t+1] = v.y;
            w[c][4*t+2] = v.z; w[c][4*t+3] = v.w;
        }
    }

    if (SYNC) wait_chunk(cnt, 0);
    // Stage chunk 0 synchronously.
    {
        const float4* g = reinterpret_cast<const float4*>(U);
        float4*       l = reinterpret_cast<float4*>(&Ulds[0][0]);
        #pragma unroll
        for (int r = 0; r < 8; ++r) l[r * 256 + tid] = g[r * 256 + tid];
    }
    if (tid < HN) h[0][tid] = 0.0f;
    __syncthreads();

    int buf = 0;
    for (int c = 0; c < NCH; ++c) {
        const int nb = buf ^ 1;
        const int cg = (c + 1 < NCH) ? (c + 1) : c;

        if (SYNC) wait_chunk(cnt, cg);         // producer gate (chunk cg ready)

        // Issue-early: chunk cg loads into registers; in flight across the chunk.
        float4 st[8];
        {
            const float4* gsrc = reinterpret_cast<const float4*>(U + cg * CH * HN);
            #pragma unroll
            for (int r = 0; r < 8; ++r) st[r] = gsrc[r * 256 + tid];
        }

        for (int s2 = 0; s2 < CH; ++s2) {
            const int hc = s2 & 1;
            const float u_cur = Ulds[buf][s2 * HN + oi_w];

            const float* base = &h[hc][jg * 16];
            float s0 = 0.f, s1 = 0.f, s2a = 0.f, s3 = 0.f;
            #pragma unroll
            for (int t = 0; t < 4; ++t) {
                const int krot = (t + rot) & 3;
                float4 hv = *reinterpret_cast<const float4*>(base + 4 * krot);
                s0  = fmaf(w[0][4*t+0], hv.x, s0);  s0  = fmaf(w[0][4*t+1], hv.y, s0);
                s0  = fmaf(w[0][4*t+2], hv.z, s0);  s0  = fmaf(w[0][4*t+3], hv.w, s0);
                s1  = fmaf(w[1][4*t+0], hv.x, s1);  s1  = fmaf(w[1][4*t+1], hv.y, s1);
                s1  = fmaf(w[1][4*t+2], hv.z, s1);  s1  = fmaf(w[1][4*t+3], hv.w, s1);
                s2a = fmaf(w[2][4*t+0], hv.x, s2a); s2a = fmaf(w[2][4*t+1], hv.y, s2a);
                s2a = fmaf(w[2][4*t+2], hv.z, s2a); s2a = fmaf(w[2][4*t+3], hv.w, s2a);
                s3  = fmaf(w[3][4*t+0], hv.x, s3);  s3  = fmaf(w[3][4*t+1], hv.y, s3);
                s3  = fmaf(w[3][4*t+2], hv.z, s3);  s3  = fmaf(w[3][4*t+3], hv.w, s3);
            }

            // 3-stage DPP reduce-scatter over the 8 jg lanes.
            const bool lo4 = !hi4;
            float t0 = lo4 ? s2a : s0;
            float t1 = lo4 ? s3  : s1;
            float x0 = (lo4 ? s0 : s2a) + dpp_xor4(t0, hi4);
            float x1 = (lo4 ? s1 : s3 ) + dpp_xor4(t1, hi4);
            const bool lo2 = (jg & 2) == 0;
            float t2 = lo2 ? x1 : x0;
            float z  = (lo2 ? x0 : x1) + dpp_xor2(t2);
            z += dpp_xor1(z);

            const float hn = fast_tanh(z + u_cur);
            if ((jg & 1) == 0) h[hc ^ 1][oi_w] = hn;
            lds_barrier();                     // lgkm-only: staging stays in flight
        }

        // Write-late: publish staged chunk (vmcnt wait ~free after 64 steps).
        {
            float4* ldst = reinterpret_cast<float4*>(&Ulds[nb][0]);
            #pragma unroll
            for (int r = 0; r < 8; ++r) ldst[r * 256 + tid] = st[r];
        }
        __syncthreads();
        buf = nb;
    }

    if (tid < HN) out[tid] = h[0][tid];
}

extern "C" void kernel_launch(void* const* d_in, const int* in_sizes, int n_in,
                              void* d_out, int out_size, void* d_ws, size_t ws_size,
                              hipStream_t stream)
{
    const float* event   = (const float*)d_in[0];
    const int*   lengths = (const int*)  d_in[1];
    const float* W_ih1   = (const float*)d_in[2];
    const float* W_hh1   = (const float*)d_in[3];
    const float* b_ih1   = (const float*)d_in[4];
    const float* b_hh1   = (const float*)d_in[5];
    const float* W_ih2   = (const float*)d_in[6];
    const float* W_hh2   = (const float*)d_in[7];
    const float* b_ih2   = (const float*)d_in[8];
    const float* b_hh2   = (const float*)d_in[9];
    float* out = (float*)d_out;                   // 128 floats
    float* U   = (float*)d_ws;                    // PN*HN floats = 2 MB
    unsigned* cnt = (unsigned*)(U + (size_t)PN * HN);

    const bool sync_ok =
        ws_size >= (size_t)PN * HN * sizeof(float) + NCH * sizeof(unsigned);

    if (sync_ok) {
        hipMemsetAsync(cnt, 0, NCH * sizeof(unsigned), stream);  // clear 0xAA poison
        net1_kernel<true><<<dim3(PN), dim3(256), 0, stream>>>(
            event, lengths, W_ih1, W_hh1, b_ih1, b_hh1, W_ih2, b_ih2, b_hh2, U, cnt);
        net2_kernel<true><<<dim3(1), dim3(256), 0, stream>>>(U, W_hh2, out, cnt);
    } else {
        net1_kernel<false><<<dim3(PN), dim3(256), 0, stream>>>(
            event, lengths, W_ih1, W_hh1, b_ih1, b_hh1, W_ih2, b_ih2, b_hh2, U, cnt);
        net2_kernel<false><<<dim3(1), dim3(256), 0, stream>>>(U, W_hh2, out, cnt);
    }
}

// Round 10
// 1557.322 us; speedup vs baseline: 1.2038x; 1.1323x over previous
//
#include <hip/hip_runtime.h>

// RNNDoubleStacked: P=4096, F=128 (ragged), H=128.
// R9 post-mortem: same-stream kernels serialize under graph capture -> the
// producer/consumer overlap needs ONE dispatch. Fused kernel, grid=4097:
//   block 0    = consumer (net2: sequential 4096-step RNN, R7 dataflow,
//                single-buffered 32KB U panel, chunk gate on ready-counters,
//                s_setprio(1) to win CU arbitration vs co-resident producers)
//   blocks 1.. = producers (net1: per-particle RNN, R8 jg16/DPP dataflow;
//                U-row store -> __syncthreads (vmcnt drain) -> one
//                RELEASE/AGENT fetch_add on cnt[p>>6])
// LDS/block = 34.3KB -> 4 blocks/CU (same producer occupancy as standalone).
// Fallback (ws too small for counters): sequential standalone kernels.

constexpr int PN = 4096;
constexpr int FN = 128;
constexpr int HN = 128;
constexpr int CH  = 64;            // particles per chunk = consumer steps/chunk
constexpr int NCH = PN / CH;       // 64 chunks

__device__ __forceinline__ float fast_tanh(float x) {
    float e = __expf(2.0f * x);
    return 1.0f - 2.0f / (e + 1.0f);
}

// Raw workgroup barrier WITHOUT a vmcnt(0) drain: lgkmcnt(0) publishes this
// wave's ds ops before arrival; "memory" clobber pins LDS ops.
__device__ __forceinline__ void lds_barrier() {
    asm volatile("s_waitcnt lgkmcnt(0)\n\ts_barrier" ::: "memory");
}

// --- DPP cross-lane ops (VALU; partners within the 16-lane DPP row) ---
__device__ __forceinline__ float dpp_xor1(float x) {
    return __int_as_float(__builtin_amdgcn_update_dpp(
        0, __float_as_int(x), 0xB1, 0xF, 0xF, true));
}
__device__ __forceinline__ float dpp_xor2(float x) {
    return __int_as_float(__builtin_amdgcn_update_dpp(
        0, __float_as_int(x), 0x4E, 0xF, 0xF, true));
}
__device__ __forceinline__ float dpp_xor4(float x, bool hi) {
    int a = __builtin_amdgcn_update_dpp(0, __float_as_int(x), 0x104, 0xF, 0xF, true);
    int b = __builtin_amdgcn_update_dpp(0, __float_as_int(x), 0x114, 0xF, 0xF, true);
    return __int_as_float(hi ? b : a);
}
__device__ __forceinline__ float dpp_xor8(float x, bool hi) {
    int a = __builtin_amdgcn_update_dpp(0, __float_as_int(x), 0x108, 0xF, 0xF, true);
    int b = __builtin_amdgcn_update_dpp(0, __float_as_int(x), 0x118, 0xF, 0xF, true);
    return __int_as_float(hi ? b : a);
}

// 16-lane reduce-scatter over 8 accumulators (producer tiling).
__device__ __forceinline__ float reduce16(const float s[8], int jg) {
    const bool hi8 = (jg & 8) != 0;
    float m0 = hi8 ? s[0] : s[4], k0 = hi8 ? s[4] : s[0];
    float m1 = hi8 ? s[1] : s[5], k1 = hi8 ? s[5] : s[1];
    float m2 = hi8 ? s[2] : s[6], k2 = hi8 ? s[6] : s[2];
    float m3 = hi8 ? s[3] : s[7], k3 = hi8 ? s[7] : s[3];
    float x0 = k0 + dpp_xor8(m0, hi8);
    float x1 = k1 + dpp_xor8(m1, hi8);
    float x2 = k2 + dpp_xor8(m2, hi8);
    float x3 = k3 + dpp_xor8(m3, hi8);
    const bool hi4 = (jg & 4) != 0;
    float y0 = (hi4 ? x2 : x0) + dpp_xor4(hi4 ? x0 : x2, hi4);
    float y1 = (hi4 ? x3 : x1) + dpp_xor4(hi4 ? x1 : x3, hi4);
    const bool hi2 = (jg & 2) != 0;
    float z  = (hi2 ? y1 : y0) + dpp_xor2(hi2 ? y0 : y1);
    z += dpp_xor1(z);
    return z;
}
__device__ __forceinline__ int reduce16_cidx(int jg) {
    return ((jg >> 3) & 1) * 4 + ((jg >> 2) & 1) * 2 + ((jg >> 1) & 1);
}

__device__ __forceinline__ void wait_chunk(const unsigned* cnt, int c) {
    while (__hip_atomic_load(&cnt[c], __ATOMIC_ACQUIRE,
                             __HIP_MEMORY_SCOPE_AGENT) < (unsigned)CH) {
        __builtin_amdgcn_s_sleep(8);           // ~512 cyc backoff per poll
    }
}

// ---------------- producer body: net1 for particle p (R8-proven) ----------------
template <bool SYNC>
__device__ __forceinline__ void net1_body(
    int p, int tid,
    const float* __restrict__ event,  const int* __restrict__ lengths,
    const float* __restrict__ W_ih1,  const float* __restrict__ W_hh1,
    const float* __restrict__ b_ih1,  const float* __restrict__ b_hh1,
    const float* __restrict__ W_ih2,  const float* __restrict__ b_ih2,
    const float* __restrict__ b_hh2,  float* __restrict__ U,
    unsigned* cnt, float (*h)[HN], float* ev)
{
    const int wv   = tid >> 6;
    const int lane = tid & 63;
    const int jg   = lane & 15;                // 8-float inner slice
    const int og16 = (wv << 2) + (lane >> 4);  // 16 groups x 8 outputs
    const int rot  = (jg >> 2) & 1;
    const int oi_w = og16 * 8 + reduce16_cidx(jg);

    if (tid < FN) ev[tid]   = event[p * FN + tid];
    if (tid < HN) h[0][tid] = 0.0f;

    float w[8][8];
    #pragma unroll
    for (int c = 0; c < 8; ++c) {
        const float* row = W_hh1 + (og16 * 8 + c) * HN + jg * 8;
        #pragma unroll
        for (int t = 0; t < 2; ++t) {
            const int krot = (t + rot) & 1;
            float4 v = *reinterpret_cast<const float4*>(row + 4 * krot);
            w[c][4*t+0] = v.x; w[c][4*t+1] = v.y;
            w[c][4*t+2] = v.z; w[c][4*t+3] = v.w;
        }
    }
    const float wx_own   = W_ih1[oi_w];
    const float bias_own = b_ih1[oi_w] + b_hh1[oi_w];
    const int   len      = lengths[p];

    __syncthreads();

    for (int t = 0; t < len; ++t) {
        const int cur = t & 1;
        const float x = ev[t];
        const float* base = &h[cur][jg * 8];
        float s[8] = {0,0,0,0,0,0,0,0};
        #pragma unroll
        for (int tt = 0; tt < 2; ++tt) {
            const int krot = (tt + rot) & 1;
            float4 hv = *reinterpret_cast<const float4*>(base + 4 * krot);
            #pragma unroll
            for (int c = 0; c < 8; ++c) {
                s[c] = fmaf(w[c][4*tt+0], hv.x, s[c]);
                s[c] = fmaf(w[c][4*tt+1], hv.y, s[c]);
                s[c] = fmaf(w[c][4*tt+2], hv.z, s[c]);
                s[c] = fmaf(w[c][4*tt+3], hv.w, s[c]);
            }
        }
        const float z  = reduce16(s, jg);
        const float hn = fast_tanh(z + fmaf(wx_own, x, bias_own));
        if ((jg & 1) == 0) h[cur ^ 1][oi_w] = hn;
        lds_barrier();
    }

    // Tail: U[p][i] = h1 . W_ih2_row_i + b_ih2[i] + b_hh2[i]
    if (tid < HN) {
        const float4* h4 = reinterpret_cast<const float4*>(h[len & 1]);
        const float4* w2 = reinterpret_cast<const float4*>(W_ih2 + tid * HN);
        float a0 = b_ih2[tid] + b_hh2[tid], a1 = 0.f, a2 = 0.f, a3 = 0.f;
        #pragma unroll
        for (int k = 0; k < HN / 4; ++k) {
            float4 hv = h4[k];
            float4 wv = w2[k];
            a0 = fmaf(wv.x, hv.x, a0);
            a1 = fmaf(wv.y, hv.y, a1);
            a2 = fmaf(wv.z, hv.z, a2);
            a3 = fmaf(wv.w, hv.w, a3);
        }
        U[p * HN + tid] = (a0 + a1) + (a2 + a3);
    }

    if (SYNC) {
        __syncthreads();   // full drain: every wave's U stores visible pre-count
        if (tid == 0) {
            __hip_atomic_fetch_add(&cnt[p >> 6], 1u,
                                   __ATOMIC_RELEASE, __HIP_MEMORY_SCOPE_AGENT);
        }
    }
}

// ---------------- consumer body: net2 (R7-proven dataflow, 1-buf panel) ----------------
template <bool SYNC>
__device__ __forceinline__ void net2_body(
    int tid,
    const float* __restrict__ U, const float* __restrict__ W_hh2,
    float* __restrict__ out, const unsigned* cnt,
    float (*h)[HN], float* Ulds)
{
    const int wv   = tid >> 6;
    const int lane = tid & 63;
    const int jg   = lane & 7;                 // 16-float inner slice
    const int ogl  = lane >> 3;
    const int og   = (wv << 3) + ogl;          // 32 groups x 4 outputs
    const int rot  = jg >> 1;
    const bool hi4 = (jg & 4) != 0;
    const int cidx = ((jg >> 2) & 1) * 2 + ((jg >> 1) & 1);
    const int oi_w = og * 4 + cidx;

    __builtin_amdgcn_s_setprio(1);             // win CU arbitration vs producers

    float w[4][16];
    #pragma unroll
    for (int c = 0; c < 4; ++c) {
        const float* row = W_hh2 + (og * 4 + c) * HN + jg * 16;
        #pragma unroll
        for (int t = 0; t < 4; ++t) {
            const int krot = (t + rot) & 3;
            float4 v = *reinterpret_cast<const float4*>(row + 4 * krot);
            w[c][4*t+0] = v.x; w[c][4*t+1] = v.y;
            w[c][4*t+2] = v.z; w[c][4*t+3] = v.w;
        }
    }

    if (SYNC) wait_chunk(cnt, 0);
    {   // stage chunk 0
        const float4* g = reinterpret_cast<const float4*>(U);
        float4*       l = reinterpret_cast<float4*>(Ulds);
        #pragma unroll
        for (int r = 0; r < 8; ++r) l[r * 256 + tid] = g[r * 256 + tid];
    }
    if (tid < HN) h[0][tid] = 0.0f;
    __syncthreads();

    for (int c = 0; c < NCH; ++c) {
        const bool has_next = (c + 1 < NCH);
        if (SYNC && has_next) wait_chunk(cnt, c + 1);

        // Issue-early: next chunk into registers; in flight across the chunk.
        float4 st[8];
        {
            const float4* gsrc = reinterpret_cast<const float4*>(
                U + (has_next ? (c + 1) : c) * CH * HN);
            #pragma unroll
            for (int r = 0; r < 8; ++r) st[r] = gsrc[r * 256 + tid];
        }

        for (int s2 = 0; s2 < CH; ++s2) {
            const int hc = s2 & 1;
            const float u_cur = Ulds[s2 * HN + oi_w];

            const float* base = &h[hc][jg * 16];
            float s0 = 0.f, s1 = 0.f, s2a = 0.f, s3 = 0.f;
            #pragma unroll
            for (int t = 0; t < 4; ++t) {
                const int krot = (t + rot) & 3;
                float4 hv = *reinterpret_cast<const float4*>(base + 4 * krot);
                s0  = fmaf(w[0][4*t+0], hv.x, s0);  s0  = fmaf(w[0][4*t+1], hv.y, s0);
                s0  = fmaf(w[0][4*t+2], hv.z, s0);  s0  = fmaf(w[0][4*t+3], hv.w, s0);
                s1  = fmaf(w[1][4*t+0], hv.x, s1);  s1  = fmaf(w[1][4*t+1], hv.y, s1);
                s1  = fmaf(w[1][4*t+2], hv.z, s1);  s1  = fmaf(w[1][4*t+3], hv.w, s1);
                s2a = fmaf(w[2][4*t+0], hv.x, s2a); s2a = fmaf(w[2][4*t+1], hv.y, s2a);
                s2a = fmaf(w[2][4*t+2], hv.z, s2a); s2a = fmaf(w[2][4*t+3], hv.w, s2a);
                s3  = fmaf(w[3][4*t+0], hv.x, s3);  s3  = fmaf(w[3][4*t+1], hv.y, s3);
                s3  = fmaf(w[3][4*t+2], hv.z, s3);  s3  = fmaf(w[3][4*t+3], hv.w, s3);
            }

            // 3-stage DPP reduce-scatter over the 8 jg lanes.
            const bool lo4 = !hi4;
            float t0 = lo4 ? s2a : s0;
            float t1 = lo4 ? s3  : s1;
            float x0 = (lo4 ? s0 : s2a) + dpp_xor4(t0, hi4);
            float x1 = (lo4 ? s1 : s3 ) + dpp_xor4(t1, hi4);
            const bool lo2 = (jg & 2) == 0;
            float t2 = lo2 ? x1 : x0;
            float z  = (lo2 ? x0 : x1) + dpp_xor2(t2);
            z += dpp_xor1(z);

            const float hn = fast_tanh(z + u_cur);
            if ((jg & 1) == 0) h[hc ^ 1][oi_w] = hn;
            lds_barrier();                     // lgkm-only: staging stays in flight
        }
        // After the final per-step barrier every wave's chunk-c reads are done
        // -> safe to overwrite the single panel. vmcnt wait on st is ~free.
        if (has_next) {
            float4* ldst = reinterpret_cast<float4*>(Ulds);
            #pragma unroll
            for (int r = 0; r < 8; ++r) ldst[r * 256 + tid] = st[r];
        }
        lds_barrier();                         // publish panel for chunk c+1
    }

    if (tid < HN) out[tid] = h[0][tid];        // each chunk ends at parity 0
}

// ---------------- kernels ----------------
__global__ __launch_bounds__(256) void fused_kernel(
    const float* __restrict__ event,  const int* __restrict__ lengths,
    const float* __restrict__ W_ih1,  const float* __restrict__ W_hh1,
    const float* __restrict__ b_ih1,  const float* __restrict__ b_hh1,
    const float* __restrict__ W_ih2,  const float* __restrict__ W_hh2,
    const float* __restrict__ b_ih2,  const float* __restrict__ b_hh2,
    float* __restrict__ U, float* __restrict__ out, unsigned* cnt)
{
    __shared__ float h[2][HN];                 // both paths
    __shared__ float ev[FN];                   // producer only
    __shared__ float Ulds[CH * HN];            // consumer only (32 KB)

    const int tid = threadIdx.x;
    if (blockIdx.x == 0) {
        net2_body<true>(tid, U, W_hh2, out, cnt, h, Ulds);
    } else {
        net1_body<true>(blockIdx.x - 1, tid, event, lengths, W_ih1, W_hh1,
                        b_ih1, b_hh1, W_ih2, b_ih2, b_hh2, U, cnt, h, ev);
    }
}

__global__ __launch_bounds__(256) void net1_only(
    const float* __restrict__ event,  const int* __restrict__ lengths,
    const float* __restrict__ W_ih1,  const float* __restrict__ W_hh1,
    const float* __restrict__ b_ih1,  const float* __restrict__ b_hh1,
    const float* __restrict__ W_ih2,  const float* __restrict__ b_ih2,
    const float* __restrict__ b_hh2,  float* __restrict__ U)
{
    __shared__ float h[2][HN];
    __shared__ float ev[FN];
    net1_body<false>(blockIdx.x, threadIdx.x, event, lengths, W_ih1, W_hh1,
                     b_ih1, b_hh1, W_ih2, b_ih2, b_hh2, U, nullptr, h, ev);
}

__global__ __launch_bounds__(256) void net2_only(
    const float* __restrict__ U, const float* __restrict__ W_hh2,
    float* __restrict__ out)
{
    __shared__ float h[2][HN];
    __shared__ float Ulds[CH * HN];
    net2_body<false>(threadIdx.x, U, W_hh2, out, nullptr, h, Ulds);
}

extern "C" void kernel_launch(void* const* d_in, const int* in_sizes, int n_in,
                              void* d_out, int out_size, void* d_ws, size_t ws_size,
                              hipStream_t stream)
{
    const float* event   = (const float*)d_in[0];
    const int*   lengths = (const int*)  d_in[1];
    const float* W_ih1   = (const float*)d_in[2];
    const float* W_hh1   = (const float*)d_in[3];
    const float* b_ih1   = (const float*)d_in[4];
    const float* b_hh1   = (const float*)d_in[5];
    const float* W_ih2   = (const float*)d_in[6];
    const float* W_hh2   = (const float*)d_in[7];
    const float* b_ih2   = (const float*)d_in[8];
    const float* b_hh2   = (const float*)d_in[9];
    float* out = (float*)d_out;                   // 128 floats
    float* U   = (float*)d_ws;                    // PN*HN floats = 2 MB
    unsigned* cnt = (unsigned*)(U + (size_t)PN * HN);

    const bool sync_ok =
        ws_size >= (size_t)PN * HN * sizeof(float) + NCH * sizeof(unsigned);

    if (sync_ok) {
        hipMemsetAsync(cnt, 0, NCH * sizeof(unsigned), stream);  // clear poison
        fused_kernel<<<dim3(PN + 1), dim3(256), 0, stream>>>(
            event, lengths, W_ih1, W_hh1, b_ih1, b_hh1,
            W_ih2, W_hh2, b_ih2, b_hh2, U, out, cnt);
    } else {
        net1_only<<<dim3(PN), dim3(256), 0, stream>>>(
            event, lengths, W_ih1, W_hh1, b_ih1, b_hh1, W_ih2, b_ih2, b_hh2, U);
        net2_only<<<dim3(1), dim3(256), 0, stream>>>(U, W_hh2, out);
    }
}